// Round 2
// baseline (525.945 us; speedup 1.0000x reference)
//
#include <hip/hip_runtime.h>
#include <hip/hip_fp16.h>

#define BB 2048
#define NN 1568
#define CD 48
#define TPB 1024
#define WSLOTS 98304   // 3 c * 4 i * 16 d * 512 ts uint4 slots (1.5 MB in d_ws)

typedef _Float16 h2v __attribute__((ext_vector_type(2)));

// ---- scalar-safe half2 helpers (no local-array casts)
__device__ __forceinline__ unsigned packh2(float a, float b) {
    __half2 h = __floats2half2_rn(a, b);
    unsigned r; __builtin_memcpy(&r, &h, 4); return r;
}
__device__ __forceinline__ float2 uph2(unsigned v) {
    __half2 h; __builtin_memcpy(&h, &v, 4); return __half22float2(h);
}
// f32 += h2 . h2  (v_dot2_f32_f16; exact same math as cvt+fma fallback)
__device__ __forceinline__ float fdot2u(unsigned a, unsigned b, float c) {
#if __has_builtin(__builtin_amdgcn_fdot2)
    h2v av, bv;
    __builtin_memcpy(&av, &a, 4); __builtin_memcpy(&bv, &b, 4);
    return __builtin_amdgcn_fdot2(av, bv, c, false);
#else
    const float2 fa = uph2(a), fb = uph2(b);
    return c + fa.x * fb.x + fa.y * fb.y;
#endif
}
__device__ __forceinline__ unsigned hadd2u(unsigned a, unsigned b) {
    __half2 ha, hb; __builtin_memcpy(&ha, &a, 4); __builtin_memcpy(&hb, &b, 4);
    __half2 r = __hadd2(ha, hb);
    unsigned q; __builtin_memcpy(&q, &r, 4); return q;
}
__device__ __forceinline__ unsigned hfma2u(unsigned a, unsigned b, unsigned c) {
    __half2 ha, hb, hc;
    __builtin_memcpy(&ha, &a, 4); __builtin_memcpy(&hb, &b, 4); __builtin_memcpy(&hc, &c, 4);
    __half2 r = __hfma2(ha, hb, hc);
    unsigned q; __builtin_memcpy(&q, &r, 4); return q;
}

// =================== K0: W fp32 -> fp16, swizzled ===================
// Wh slot layout: [ (c*4+i)*16 + d ][ ts ]  (uint4 = 8 fp16 = all e of one d),
// covering n = i*512 + ts. Fused-kernel wave loads are fully coalesced.
__global__ __launch_bounds__(256)
void wcast(const float* __restrict__ W, uint4* __restrict__ Wh)
{
    const int id = blockIdx.x * 256 + threadIdx.x;   // 0..24575
    const int ts = id & 511;
    const int r  = id >> 9;        // 0..47
    const int dq = r & 3;          // d quad (4 d per thread)
    const int ci = r >> 2;         // c*4+i, 0..11
    const int i  = ci & 3;
    const int c  = ci >> 2;
    const int n  = i * 512 + ts;
    uint4* dst = Wh + (size_t)ci * 8192 + dq * 4 * 512 + ts;
    if (n < NN) {
        const float* src = W + ((size_t)(c * NN + n)) * 128 + dq * 32;
#pragma unroll
        for (int dd = 0; dd < 4; ++dd) {
            const float4 f0 = *(const float4*)(src + dd * 8);
            const float4 f1 = *(const float4*)(src + dd * 8 + 4);
            uint4 q;
            q.x = packh2(f0.x, f0.y); q.y = packh2(f0.z, f0.w);
            q.z = packh2(f1.x, f1.y); q.w = packh2(f1.z, f1.w);
            dst[dd * 512] = q;
        }
    } else {
        const uint4 z = make_uint4(0u, 0u, 0u, 0u);
#pragma unroll
        for (int dd = 0; dd < 4; ++dd) dst[dd * 512] = z;
    }
}

// =================== K1: fully fused capsule routing ===================
// One 1024-thread block (16 waves -> 4 waves/SIMD) per batch.
// u (1568 x 48 fp16) in LDS, row stride 25 words (odd -> conflict-free b32).
// All fp16 math via v_dot2_f32_f16 / v_pk_fma_f16 (no unpack cvts).
__global__ __launch_bounds__(TPB, 4)
void fused(const float* __restrict__ x, const uint4* __restrict__ Wh,
           float* __restrict__ out)
{
    __shared__ unsigned ul[NN * 25];     // 156,800 B
    __shared__ float red[16][CD];        //   3,072 B
    __shared__ float vsh[CD];            //     192 B
    __shared__ unsigned vsh2[24];        //      96 B  => 160,160 <= 163,840

    const int t = threadIdx.x;
    const int w = t >> 6;
    const int b = blockIdx.x;
    const float* xb = x + (size_t)b * NN * 8;

    unsigned acc2[24];                   // half2 pair sums (<=2 adds/thread)
#pragma unroll
    for (int j = 0; j < 24; ++j) acc2[j] = 0u;

    // ---------------- phase A: u = W.x -> LDS, + pass-0 sum ----------------
#pragma unroll 1
    for (int i = 0; i < 2; ++i) {
        const int n = i * 1024 + t;
        if (n < NN) {
            const float4 xa = __ldg((const float4*)(xb + n * 8));
            const float4 xc = __ldg((const float4*)(xb + n * 8 + 4));
            const unsigned xh0 = packh2(xa.x, xa.y);
            const unsigned xh1 = packh2(xa.z, xa.w);
            const unsigned xh2 = packh2(xc.x, xc.y);
            const unsigned xh3 = packh2(xc.z, xc.w);
            const int g  = n >> 9;       // 512-group
            const int ts = n & 511;
            unsigned* row = ul + n * 25;

            // C3 literal -> acc2[] indexing stays static (no scratch).
#define DO_C(C3) { \
            const uint4* wp = Wh + (size_t)(((C3) * 4 + g)) * 8192 + ts; \
            _Pragma("unroll") \
            for (int dh = 0; dh < 2; ++dh) { \
                uint4 wr[8]; \
                _Pragma("unroll") \
                for (int d = 0; d < 8; ++d) wr[d] = wp[(dh * 8 + d) * 512]; \
                float uv[8]; \
                _Pragma("unroll") \
                for (int d = 0; d < 8; ++d) \
                    uv[d] = fdot2u(wr[d].x, xh0, fdot2u(wr[d].y, xh1, \
                            fdot2u(wr[d].z, xh2, fdot2u(wr[d].w, xh3, 0.f)))); \
                _Pragma("unroll") \
                for (int k = 0; k < 4; ++k) { \
                    const unsigned ph = packh2(uv[2*k], uv[2*k+1]); \
                    row[(C3) * 8 + dh * 4 + k] = ph; \
                    acc2[(C3) * 8 + dh * 4 + k] = hadd2u(acc2[(C3) * 8 + dh * 4 + k], ph); \
                } \
            } }

            DO_C(0)
            DO_C(1)
            DO_C(2)
#undef DO_C
        }
    }
    __syncthreads();

#define REDUCE_ACC(ARR) { \
    _Pragma("unroll") \
    for (int j = 0; j < CD; ++j) { \
        float v_ = ARR[j]; \
        v_ += __shfl_xor(v_, 1);  v_ += __shfl_xor(v_, 2); \
        v_ += __shfl_xor(v_, 4);  v_ += __shfl_xor(v_, 8); \
        v_ += __shfl_xor(v_, 16); v_ += __shfl_xor(v_, 32); \
        ARR[j] = v_; \
    } \
    if ((t & 63) == 0) { \
        _Pragma("unroll") \
        for (int j = 0; j < CD; ++j) red[w][j] = ARR[j]; \
    } }

#define SUM16(T) (red[0][T]+red[1][T]+red[2][T]+red[3][T]+red[4][T]+red[5][T] \
                 +red[6][T]+red[7][T]+red[8][T]+red[9][T]+red[10][T]+red[11][T] \
                 +red[12][T]+red[13][T]+red[14][T]+red[15][T])

    {
        float acc[CD];
#pragma unroll
        for (int j = 0; j < 24; ++j) {
            const float2 g2 = uph2(acc2[j]);
            acc[2*j] = g2.x; acc[2*j+1] = g2.y;
        }
        REDUCE_ACC(acc)
    }
    __syncthreads();
    if (t < CD) {
        const float s = SUM16(t) * (1.0f / 3.0f);
        float q = s * s;
        q += __shfl_xor(q, 1); q += __shfl_xor(q, 2); q += __shfl_xor(q, 4); q += __shfl_xor(q, 8);
        vsh[t] = s * sqrtf(q) / (1.f + q);       // v1
    }
    __syncthreads();
    if (t < 24) vsh2[t] = packh2(vsh[2*t], vsh[2*t+1]);
    __syncthreads();

    // ---------------- passes 1,2 (u from LDS, all-fp16 inner math) ----------------
#pragma unroll 1
    for (int pass = 1; pass <= 2; ++pass) {
        unsigned wv2[24];
#pragma unroll
        for (int j = 0; j < 24; ++j) wv2[j] = vsh2[j];
        unsigned a2[24];
#pragma unroll
        for (int j = 0; j < 24; ++j) a2[j] = 0u;

#pragma unroll 1
        for (int i = 0; i < 2; ++i) {
            const int n = i * 1024 + t;
            if (n < NN) {
                const unsigned* row = ul + n * 25;
                unsigned f[24];
#pragma unroll
                for (int j = 0; j < 24; ++j) f[j] = row[j];
                float l0 = 0.f, l1 = 0.f, l2 = 0.f;
#pragma unroll
                for (int j = 0; j < 8; ++j) {
                    l0 = fdot2u(f[j],      wv2[j],      l0);
                    l1 = fdot2u(f[8 + j],  wv2[8 + j],  l1);
                    l2 = fdot2u(f[16 + j], wv2[16 + j], l2);
                }
                // |logit| < ~0.2 — no max-shift needed
                const float e0 = __expf(l0), e1 = __expf(l1), e2 = __expf(l2);
                const float inv = 1.f / (e0 + e1 + e2);
                const unsigned c0h = packh2(e0 * inv, e0 * inv);
                const unsigned c1h = packh2(e1 * inv, e1 * inv);
                const unsigned c2h = packh2(e2 * inv, e2 * inv);
#pragma unroll
                for (int j = 0; j < 8; ++j) {
                    a2[j]      = hfma2u(c0h, f[j],      a2[j]);
                    a2[8 + j]  = hfma2u(c1h, f[8 + j],  a2[8 + j]);
                    a2[16 + j] = hfma2u(c2h, f[16 + j], a2[16 + j]);
                }
            }
        }
        {
            float acc[CD];
#pragma unroll
            for (int j = 0; j < 24; ++j) {
                const float2 g2 = uph2(a2[j]);
                acc[2*j] = g2.x; acc[2*j+1] = g2.y;
            }
            REDUCE_ACC(acc)
        }
        __syncthreads();
        if (t < CD) {
            const float s = SUM16(t);
            float q = s * s;
            q += __shfl_xor(q, 1); q += __shfl_xor(q, 2); q += __shfl_xor(q, 4); q += __shfl_xor(q, 8);
            const float v = s * sqrtf(q) / (1.f + q);
            if (pass == 1) vsh[t] += v;                       // w2 = v1 + v2
            else           out[(size_t)b * CD + t] = v;       // final
        }
        __syncthreads();
        if (pass == 1) {
            if (t < 24) vsh2[t] = packh2(vsh[2*t], vsh[2*t+1]);
            __syncthreads();
        }
    }
#undef REDUCE_ACC
#undef SUM16
}

extern "C" void kernel_launch(void* const* d_in, const int* in_sizes, int n_in,
                              void* d_out, int out_size, void* d_ws, size_t ws_size,
                              hipStream_t stream) {
    (void)in_sizes; (void)n_in; (void)out_size;
    const float* x = (const float*)d_in[0];   // (B, N, 8) fp32
    const float* W = (const float*)d_in[1];   // (1, 3, N, 16, 8) fp32
    if (ws_size < (size_t)WSLOTS * 16) return;
    uint4* Wh = (uint4*)d_ws;

    hipLaunchKernelGGL(wcast, dim3(96), dim3(256), 0, stream, W, Wh);
    hipLaunchKernelGGL(fused, dim3(BB), dim3(TPB), 0, stream, x, Wh, (float*)d_out);
}